// Round 4
// baseline (185.876 us; speedup 1.0000x reference)
//
#include <hip/hip_runtime.h>

// QuantileLoss: mean over [ (p0-t0)^2, (p1-t1)^2, (p2-t2)^2, lower, upper ]
//   lower = p3>p2 ? (p4-t2)*4 : (p3>0.95*t2 ? 0 : (p3-0.95*t2)^2)
//   upper = p4<p2 ? (p4-t2)*4 : (p4<1.05*t2 ? 0 : (p4-1.05*t2)^2)
//
// R3 post-mortem: atomics removed -> ql_main ~42us (off top-5; harness's own
// 335MB ws-poison fills at ~50us dominate the profile and are fixed cost).
// R4: (a) 2048 blocks = 8 waves/SIMD full occupancy; (b) 2-deep register
// pipeline so the ds_write of tile k waits on loads issued TWO iterations ago
// (vmcnt never drains the k+1 loads); wave-private LDS tiles, zero barriers
// in the hot loop, odd-stride (5/3) conflict-free LDS readback, per-block
// partial sums + tiny finalize (no atomics).

#define BLOCK 256
#define NBLK  2048
#define WAVES_PER_BLOCK (BLOCK / 64)

__device__ __forceinline__ float row_loss(float p0, float p1, float p2,
                                          float p3, float p4,
                                          float t0, float t1, float t2) {
    float d0 = p0 - t0, d1 = p1 - t1, d2 = p2 - t2;
    float acc = d0 * d0 + d1 * d1 + d2 * d2;
    float tl = t2 * 0.95f;
    float tu = t2 * 1.05f;
    float pen = (p4 - t2) * 4.0f;
    float dl = p3 - tl;
    float du = p4 - tu;
    float lower = (p3 > p2) ? pen : ((p3 > tl) ? 0.0f : dl * dl);
    float upper = (p4 < p2) ? pen : ((p4 < tu) ? 0.0f : du * du);
    return acc + lower + upper;
}

__global__ __launch_bounds__(BLOCK, 8) void ql_main(const float* __restrict__ preds,
                                                    const float* __restrict__ target,
                                                    double* __restrict__ ws,
                                                    long ntiles) {
    // per-wave region: 80 float4 preds (64 rows x 5) + 48 float4 target (64 x 3)
    __shared__ float4 sbuf[WAVES_PER_BLOCK][128];
    __shared__ double wsum[WAVES_PER_BLOCK];

    const int lane = threadIdx.x & 63;
    const int w = threadIdx.x >> 6;
    const long gwave = (long)blockIdx.x * WAVES_PER_BLOCK + w;
    const long nw = (long)gridDim.x * WAVES_PER_BLOCK;

    const float4* pb4 = (const float4*)preds;
    const float4* tb4 = (const float4*)target;
    float* sp = (float*)&sbuf[w][0];    // 320 floats: preds rows, stride 5
    float* st = (float*)&sbuf[w][80];   // 192 floats: target rows, stride 3

    const int idx1 = (lane < 16) ? (64 + lane) : (80 + lane - 16);

    float acc = 0.0f;

    // ---- 2-deep prologue: tiles t and t+nw in registers
    float4 r0[2], r1[2];
    if (gwave < ntiles) {
        r0[0] = pb4[gwave * 80 + lane];
        r1[0] = (lane < 16) ? pb4[gwave * 80 + 64 + lane] : tb4[gwave * 48 + (lane - 16)];
    }
    if (gwave + nw < ntiles) {
        long t1i = gwave + nw;
        r0[1] = pb4[t1i * 80 + lane];
        r1[1] = (lane < 16) ? pb4[t1i * 80 + 64 + lane] : tb4[t1i * 48 + (lane - 16)];
    }

    int buf = 0;
    for (long t = gwave; t < ntiles; t += nw) {
        // stage tile t (registers loaded 2 iterations ago -> vmcnt wait leaves
        // the newer tile's loads in flight)
        sbuf[w][lane] = r0[buf];
        sbuf[w][idx1] = r1[buf];

        // prefetch tile t + 2*nw into the buffer slot just freed
        long tp = t + 2 * nw;
        if (tp < ntiles) {
            r0[buf] = pb4[tp * 80 + lane];
            r1[buf] = (lane < 16) ? pb4[tp * 80 + 64 + lane] : tb4[tp * 48 + (lane - 16)];
        }

        // consume: one row per lane; stride 5/3 -> conflict-free (odd stride)
        acc += row_loss(sp[5 * lane + 0], sp[5 * lane + 1], sp[5 * lane + 2],
                        sp[5 * lane + 3], sp[5 * lane + 4],
                        st[3 * lane + 0], st[3 * lane + 1], st[3 * lane + 2]);

        buf ^= 1;
    }

    // wave reduction (double), cross-wave via LDS, one plain store per block
    double dacc = (double)acc;
#pragma unroll
    for (int off = 32; off > 0; off >>= 1)
        dacc += __shfl_down(dacc, off, 64);
    if (lane == 0) wsum[w] = dacc;
    __syncthreads();
    if (threadIdx.x == 0)
        ws[blockIdx.x] = wsum[0] + wsum[1] + wsum[2] + wsum[3];
}

__global__ __launch_bounds__(256) void ql_finalize(const double* __restrict__ ws,
                                                   const float* __restrict__ preds,
                                                   const float* __restrict__ target,
                                                   float* __restrict__ out,
                                                   long rows, long tail_start) {
    __shared__ double wsum[4];
    const int tid = threadIdx.x;

    double d = 0.0;
#pragma unroll
    for (int i = 0; i < NBLK / 256; ++i)
        d += ws[tid + i * 256];

    // leftover rows not covered by full 64-row tiles (none for N=4194304)
    for (long r = tail_start + tid; r < rows; r += 256) {
        const float* p = preds + r * 5;
        const float* tg = target + r * 3;
        d += (double)row_loss(p[0], p[1], p[2], p[3], p[4], tg[0], tg[1], tg[2]);
    }

#pragma unroll
    for (int off = 32; off > 0; off >>= 1)
        d += __shfl_down(d, off, 64);
    int lane = tid & 63, w = tid >> 6;
    if (lane == 0) wsum[w] = d;
    __syncthreads();
    if (tid == 0) {
        double total = wsum[0] + wsum[1] + wsum[2] + wsum[3];
        out[0] = (float)(total / ((double)rows * 5.0));
    }
}

extern "C" void kernel_launch(void* const* d_in, const int* in_sizes, int n_in,
                              void* d_out, int out_size, void* d_ws, size_t ws_size,
                              hipStream_t stream) {
    const float* preds = (const float*)d_in[0];
    const float* target = (const float*)d_in[1];
    long rows = (long)in_sizes[0] / 5;
    long ntiles = rows / 64;            // full 64-row tiles
    long tail_start = ntiles * 64;

    double* partials = (double*)d_ws;   // NBLK doubles = 16 KB

    ql_main<<<NBLK, BLOCK, 0, stream>>>(preds, target, partials, ntiles);
    ql_finalize<<<1, 256, 0, stream>>>(partials, preds, target,
                                       (float*)d_out, rows, tail_start);
}

// Round 5
// 159.338 us; speedup vs baseline: 1.1665x; 1.1665x over previous
//
#include <hip/hip_runtime.h>

// QuantileLoss: mean over [ (p0-t0)^2, (p1-t1)^2, (p2-t2)^2, lower, upper ]
//   lower = p3>p2 ? (p4-t2)*4 : (p3>0.95*t2 ? 0 : (p3-0.95*t2)^2)
//   upper = p4<p2 ? (p4-t2)*4 : (p4<1.05*t2 ? 0 : (p4-1.05*t2)^2)
//
// R4 post-mortem: r0[buf]/r1[buf] dynamic indexing sent the pipeline
// registers to SCRATCH (VGPR_Count=16, WRITE_SIZE=65MB) -> 74us. R5: same
// 2-deep pipeline but manually unrolled x2 with named registers a0/a1/b0/b1
// so everything stays in VGPRs. 2048 blocks = 8 waves/SIMD full occupancy;
// wave-private LDS tiles; zero barriers in hot loop; odd-stride (5/3)
// conflict-free LDS readback; per-block partials + finalize (no atomics).

#define BLOCK 256
#define NBLK  2048
#define WAVES_PER_BLOCK (BLOCK / 64)

__device__ __forceinline__ float row_loss(float p0, float p1, float p2,
                                          float p3, float p4,
                                          float t0, float t1, float t2) {
    float d0 = p0 - t0, d1 = p1 - t1, d2 = p2 - t2;
    float acc = d0 * d0 + d1 * d1 + d2 * d2;
    float tl = t2 * 0.95f;
    float tu = t2 * 1.05f;
    float pen = (p4 - t2) * 4.0f;
    float dl = p3 - tl;
    float du = p4 - tu;
    float lower = (p3 > p2) ? pen : ((p3 > tl) ? 0.0f : dl * dl);
    float upper = (p4 < p2) ? pen : ((p4 < tu) ? 0.0f : du * du);
    return acc + lower + upper;
}

// one wave-tile = 64 rows: 80 float4 of preds + 48 float4 of target
#define LOADT(tt, ra, rb)                                                      \
    do {                                                                       \
        ra = pb4[(tt) * 80 + lane];                                            \
        rb = (lane < 16) ? pb4[(tt) * 80 + 64 + lane]                          \
                         : tb4[(tt) * 48 + (lane - 16)];                       \
    } while (0)

#define CONSUME()                                                              \
    row_loss(sp[5 * lane + 0], sp[5 * lane + 1], sp[5 * lane + 2],             \
             sp[5 * lane + 3], sp[5 * lane + 4],                               \
             st[3 * lane + 0], st[3 * lane + 1], st[3 * lane + 2])

__global__ __launch_bounds__(BLOCK, 8) void ql_main(const float* __restrict__ preds,
                                                    const float* __restrict__ target,
                                                    double* __restrict__ ws,
                                                    long ntiles) {
    __shared__ float4 sbuf[WAVES_PER_BLOCK][128];
    __shared__ double wsum[WAVES_PER_BLOCK];

    const int lane = threadIdx.x & 63;
    const int w = threadIdx.x >> 6;
    const long gwave = (long)blockIdx.x * WAVES_PER_BLOCK + w;
    const long nw = (long)gridDim.x * WAVES_PER_BLOCK;

    const float4* pb4 = (const float4*)preds;
    const float4* tb4 = (const float4*)target;
    float* sp = (float*)&sbuf[w][0];    // 320 floats: preds rows, stride 5
    float* st = (float*)&sbuf[w][80];   // 192 floats: target rows, stride 3

    float acc = 0.0f;
    long t = gwave;
    if (t < ntiles) {
        float4 a0 = {}, a1 = {}, b0 = {}, b1 = {};
        LOADT(t, a0, a1);
        if (t + nw < ntiles) LOADT(t + nw, b0, b1);

        for (;;) {
            // ---- stage & consume tile t from A regs; prefetch t+2nw into A
            sbuf[w][lane] = a0;
            sbuf[w][64 + lane] = a1;
            if (t + 2 * nw < ntiles) LOADT(t + 2 * nw, a0, a1);
            acc += CONSUME();
            t += nw;
            if (t >= ntiles) break;

            // ---- stage & consume tile t from B regs; prefetch t+2nw into B
            sbuf[w][lane] = b0;
            sbuf[w][64 + lane] = b1;
            if (t + 2 * nw < ntiles) LOADT(t + 2 * nw, b0, b1);
            acc += CONSUME();
            t += nw;
            if (t >= ntiles) break;
        }
    }

    // wave reduction (double), cross-wave via LDS, one plain store per block
    double dacc = (double)acc;
#pragma unroll
    for (int off = 32; off > 0; off >>= 1)
        dacc += __shfl_down(dacc, off, 64);
    if (lane == 0) wsum[w] = dacc;
    __syncthreads();
    if (threadIdx.x == 0)
        ws[blockIdx.x] = wsum[0] + wsum[1] + wsum[2] + wsum[3];
}

__global__ __launch_bounds__(256) void ql_finalize(const double* __restrict__ ws,
                                                   const float* __restrict__ preds,
                                                   const float* __restrict__ target,
                                                   float* __restrict__ out,
                                                   long rows, long tail_start) {
    __shared__ double wsum[4];
    const int tid = threadIdx.x;

    double d = 0.0;
#pragma unroll
    for (int i = 0; i < NBLK / 256; ++i)
        d += ws[tid + i * 256];

    // leftover rows not covered by full 64-row tiles (none for N=4194304)
    for (long r = tail_start + tid; r < rows; r += 256) {
        const float* p = preds + r * 5;
        const float* tg = target + r * 3;
        d += (double)row_loss(p[0], p[1], p[2], p[3], p[4], tg[0], tg[1], tg[2]);
    }

#pragma unroll
    for (int off = 32; off > 0; off >>= 1)
        d += __shfl_down(d, off, 64);
    int lane = tid & 63, w = tid >> 6;
    if (lane == 0) wsum[w] = d;
    __syncthreads();
    if (tid == 0) {
        double total = wsum[0] + wsum[1] + wsum[2] + wsum[3];
        out[0] = (float)(total / ((double)rows * 5.0));
    }
}

extern "C" void kernel_launch(void* const* d_in, const int* in_sizes, int n_in,
                              void* d_out, int out_size, void* d_ws, size_t ws_size,
                              hipStream_t stream) {
    const float* preds = (const float*)d_in[0];
    const float* target = (const float*)d_in[1];
    long rows = (long)in_sizes[0] / 5;
    long ntiles = rows / 64;            // full 64-row tiles
    long tail_start = ntiles * 64;

    double* partials = (double*)d_ws;   // NBLK doubles = 16 KB

    ql_main<<<NBLK, BLOCK, 0, stream>>>(preds, target, partials, ntiles);
    ql_finalize<<<1, 256, 0, stream>>>(partials, preds, target,
                                       (float*)d_out, rows, tail_start);
}